// Round 1
// baseline (105.322 us; speedup 1.0000x reference)
//
#include <hip/hip_runtime.h>

// Problem constants (B, L, H, D, T) = (8, 4096, 8, 128, 128)
constexpr int B = 8;
constexpr int L = 4096;
constexpr int H = 8;
constexpr int D = 128;
constexpr int T = 128;

constexpr int ROW   = H * D;        // 1024 floats per (b, p) row
constexpr int ROW4  = ROW / 4;      // 256 float4 per row
constexpr long long KV_ELEMS = (long long)B * L * ROW;   // 33,554,432 floats per tensor
constexpr long long TOTAL4   = KV_ELEMS / 4;             // 8,388,608 float4 per tensor

__global__ __launch_bounds__(256) void kv_cache_update(
    const float4* __restrict__ keys,
    const float4* __restrict__ values,
    const int*    __restrict__ lengths,
    const float4* __restrict__ new_keys,
    const float4* __restrict__ new_values,
    const int*    __restrict__ new_lengths,
    float4* __restrict__ out_k,
    float4* __restrict__ out_v,
    float*  __restrict__ out_len)
{
    const long long stride = (long long)gridDim.x * blockDim.x;
    for (long long i = (long long)blockIdx.x * blockDim.x + threadIdx.x;
         i < TOTAL4; i += stride) {
        // i indexes float4 units. 256 float4 per row -> one block-iteration
        // spans exactly one row, so the branch below is wave-uniform.
        const int row = (int)(i >> 8);      // / ROW4
        const int c   = (int)(i & 255);     // float4 index within row
        const int b   = row >> 12;          // / L
        const int p   = row & 4095;         // % L

        const int l  = lengths[b];          // L1/L2-broadcast scalar loads
        const int nl = new_lengths[b];

        float4 vk, vv;
        if (p >= l && p < l + nl) {
            // row comes from the new tokens: source token index = p - l
            const long long nidx = ((long long)(b * T + (p - l)) << 8) + c;
            vk = new_keys[nidx];
            vv = new_values[nidx];
        } else {
            vk = keys[i];
            vv = values[i];
        }
        out_k[i] = vk;
        out_v[i] = vv;
    }

    // updated_lengths, written as numeric float values (out buffer is f32)
    if (blockIdx.x == 0 && threadIdx.x < B) {
        const int b = threadIdx.x;
        out_len[b] = (float)(lengths[b] + new_lengths[b]);
    }
}

extern "C" void kernel_launch(void* const* d_in, const int* in_sizes, int n_in,
                              void* d_out, int out_size, void* d_ws, size_t ws_size,
                              hipStream_t stream)
{
    const float4* keys       = (const float4*)d_in[0];
    const float4* values     = (const float4*)d_in[1];
    const int*    lengths    = (const int*)   d_in[2];
    const float4* new_keys   = (const float4*)d_in[3];
    const float4* new_values = (const float4*)d_in[4];
    const int*    new_lengths= (const int*)   d_in[5];

    float* out   = (float*)d_out;
    float4* out_k = (float4*)out;
    float4* out_v = (float4*)(out + KV_ELEMS);
    float*  out_len = out + 2 * KV_ELEMS;

    // Memory-bound: ~2048 blocks + grid-stride (Guideline 11)
    kv_cache_update<<<2048, 256, 0, stream>>>(
        keys, values, lengths, new_keys, new_values, new_lengths,
        out_k, out_v, out_len);
}